// Round 6
// baseline (5372.157 us; speedup 1.0000x reference)
//
#include <hip/hip_runtime.h>
#include <stdint.h>

namespace {

constexpr int B_   = 512;
constexpr int T_   = 512;
constexpr int IN_  = 6;
constexpr int H_   = 64;
constexpr int HH_  = 128;
constexpr int OUT_ = 8;

typedef _Float16 f16x2 __attribute__((ext_vector_type(2)));

__device__ __forceinline__ float dot2f(uint32_t w, uint32_t z, float acc) {
    return __builtin_amdgcn_fdot2(__builtin_bit_cast(f16x2, w),
                                  __builtin_bit_cast(f16x2, z), acc, false);
}

__device__ __forceinline__ uint32_t pack2f(float a, float b) {
    f16x2 p;
    p[0] = (_Float16)a;
    p[1] = (_Float16)b;
    return __builtin_bit_cast(uint32_t, p);
}

// sum across a 4-lane quad (kq = lane&3) via DPP quad_perm — pure VALU.
__device__ __forceinline__ float qsum4(float v) {
    int y = __builtin_amdgcn_mov_dpp(__builtin_bit_cast(int, v), 0xB1, 0xF, 0xF, true); // xor1
    v += __builtin_bit_cast(float, y);
    y = __builtin_amdgcn_mov_dpp(__builtin_bit_cast(int, v), 0x4E, 0xF, 0xF, true);     // xor2
    return v + __builtin_bit_cast(float, y);
}

__device__ __forceinline__ float tanh_fast(float v) {
    float ax = fabsf(v);
    float e  = __expf(2.0f * ax);
    float r  = 1.0f - 2.0f / (e + 1.0f);
    return copysignf(r, v);
}

// One workgroup (512 threads) per batch element.
//   thread t: column c = t>>2, k-quarter kq = t&3.
//   88 packed-f16-pair weight u32/thread; launch_bounds(512,2) -> 256-reg cap,
//   expected to land at the 128 granule (4 waves/SIMD, 2 blocks/CU).
//   LDS layouts are the round-3/5 conflict-free ones (flat pp, scalar reads).
__global__ __launch_bounds__(512, 2) void cde_kernel(
    const float* __restrict__ x,
    const float* __restrict__ W_init, const float* __restrict__ b_init,
    const float* __restrict__ W_in,   const float* __restrict__ b_in,
    const float* __restrict__ W_h1,   const float* __restrict__ b_h1,
    const float* __restrict__ W_h2,   const float* __restrict__ b_h2,
    const float* __restrict__ W_out,  const float* __restrict__ b_out,
    const float* __restrict__ W_fin,  const float* __restrict__ b_fin,
    float* __restrict__ out)
{
    const int b  = blockIdx.x;
    const int t  = threadIdx.x;
    const int c  = t >> 2;      // 0..127
    const int kq = t & 3;       // k-quarter

    __shared__ alignas(16) uint32_t hinu[H_ / 2];    // 64 f16 (vf input h)
    __shared__ alignas(16) uint32_t zAu[HH_ / 2];    // 128 f16 ping
    __shared__ alignas(16) uint32_t zBu[HH_ / 2];    // 128 f16 pong
    __shared__ float pp[H_ * IN_];                   // flat tanh(A)*dx (0-conflict layout)
    __shared__ float dxs[IN_];
    __shared__ float hbuf[H_];

    // ---- register-resident f16 weights (k-quarter slice) ----
    uint32_t w1[8], w2[16], w3[16], w4[48];
    #pragma unroll
    for (int i = 0; i < 8; ++i) {
        int k = kq * 16 + 2 * i;
        w1[i] = pack2f(W_in[k * HH_ + c], W_in[(k + 1) * HH_ + c]);
    }
    #pragma unroll
    for (int i = 0; i < 16; ++i) {
        int k = kq * 32 + 2 * i;
        w2[i] = pack2f(W_h1[k * HH_ + c], W_h1[(k + 1) * HH_ + c]);
        w3[i] = pack2f(W_h2[k * HH_ + c], W_h2[(k + 1) * HH_ + c]);
    }
    #pragma unroll
    for (int j = 0; j < 3; ++j) {
        const int cc = c + 128 * j;
        #pragma unroll
        for (int i = 0; i < 16; ++i) {
            int k = kq * 32 + 2 * i;
            w4[j * 16 + i] = pack2f(W_out[k * 384 + cc], W_out[(k + 1) * 384 + cc]);
        }
    }
    const float bin_r = b_in[c];
    const float bh1_r = b_h1[c];
    const float bh2_r = b_h2[c];
    const float bo0 = b_out[c], bo1 = b_out[c + 128], bo2 = b_out[c + 256];
    const int   m0 = c % 6, m1 = (c + 128) % 6, m2 = (c + 256) % 6;
    const float bfin_r = (t < OUT_) ? b_fin[t] : 0.0f;

    // W_fin rows in registers for the out-stage (wave 0 only uses them).
    float wfr[8];
    #pragma unroll
    for (int j = 0; j < 8; ++j)
        wfr[j] = (t < 64) ? W_fin[((t >> 3) * 8 + j) * OUT_ + (t & 7)] : 0.0f;

    const size_t xbase = (size_t)b * T_ * IN_;
    const size_t obase = (size_t)b * T_ * OUT_;

    float xa = 0.f, xb = 0.f;
    if (t < IN_) {
        xa = x[xbase + t];
        xb = x[xbase + IN_ + t];
    }

    // ---- h0 = x[:,0] @ W_init + b_init (wave 0) ----
    float h_reg = 0.f, hacc = 0.f;
    if (t < H_) {
        float s = b_init[t];
        #pragma unroll
        for (int i = 0; i < IN_; ++i) s += x[xbase + i] * W_init[i * H_ + t];
        h_reg = s;
        hbuf[t] = s;
        ((_Float16*)hinu)[t] = (_Float16)s;
    }
    __syncthreads();

    // out for t = 0
    if (t < 64) {
        int o = t & 7, part = t >> 3;
        float s = 0.f;
        #pragma unroll
        for (int j = 0; j < 8; ++j) s += hbuf[part * 8 + j] * wfr[j];
        s += __shfl_xor(s, 8);
        s += __shfl_xor(s, 16);
        s += __shfl_xor(s, 32);
        if (part == 0) out[obase + o] = s + bfin_r;
    }

    for (int step = 0; step < T_ - 1; ++step) {
        // dxs write: readers (G4) are >=3 barriers ahead; previous step's
        // readers were >=2 barriers behind. Ordered via the G1 barrier.
        if (t < IN_) {
            dxs[t] = xb - xa;
            xa = xb;
            if (step + 2 < T_) xb = x[xbase + (size_t)(step + 2) * IN_ + t];
        }

        #pragma unroll
        for (int s4 = 0; s4 < 4; ++s4) {
            // ---- G1: h(64) -> z1(128) into zA ----
            {
                const uint32_t* hp = hinu + kq * 8;
                uint4 q0 = *reinterpret_cast<const uint4*>(hp);
                uint4 q1 = *reinterpret_cast<const uint4*>(hp + 4);
                float a = 0.f, d = 0.f;
                a = dot2f(w1[0], q0.x, a); d = dot2f(w1[1], q0.y, d);
                a = dot2f(w1[2], q0.z, a); d = dot2f(w1[3], q0.w, d);
                a = dot2f(w1[4], q1.x, a); d = dot2f(w1[5], q1.y, d);
                a = dot2f(w1[6], q1.z, a); d = dot2f(w1[7], q1.w, d);
                float z = fmaxf(bin_r + qsum4(a + d), 0.f);
                if (kq == 0) ((_Float16*)zAu)[c] = (_Float16)z;
            }
            __syncthreads();

            // ---- G2: zA -> z2 into zB ----
            {
                const uint32_t* zp = zAu + kq * 16;
                float a = 0.f, d = 0.f;
                #pragma unroll
                for (int q = 0; q < 4; ++q) {
                    uint4 zz = *reinterpret_cast<const uint4*>(zp + 4 * q);
                    a = dot2f(w2[4 * q + 0], zz.x, a); d = dot2f(w2[4 * q + 1], zz.y, d);
                    a = dot2f(w2[4 * q + 2], zz.z, a); d = dot2f(w2[4 * q + 3], zz.w, d);
                }
                float z = fmaxf(bh1_r + qsum4(a + d), 0.f);
                if (kq == 0) ((_Float16*)zBu)[c] = (_Float16)z;
            }
            __syncthreads();

            // ---- G3: zB -> z3 into zA ----
            {
                const uint32_t* zp = zBu + kq * 16;
                float a = 0.f, d = 0.f;
                #pragma unroll
                for (int q = 0; q < 4; ++q) {
                    uint4 zz = *reinterpret_cast<const uint4*>(zp + 4 * q);
                    a = dot2f(w3[4 * q + 0], zz.x, a); d = dot2f(w3[4 * q + 1], zz.y, d);
                    a = dot2f(w3[4 * q + 2], zz.z, a); d = dot2f(w3[4 * q + 3], zz.w, d);
                }
                float z = fmaxf(bh2_r + qsum4(a + d), 0.f);
                if (kq == 0) ((_Float16*)zAu)[c] = (_Float16)z;
            }
            __syncthreads();

            // ---- G4: z3 -> 384 cols, tanh, * dX ----
            {
                const uint32_t* zp = zAu + kq * 16;
                float a0 = 0.f, a1 = 0.f, a2 = 0.f;
                #pragma unroll
                for (int q = 0; q < 4; ++q) {
                    uint4 zz = *reinterpret_cast<const uint4*>(zp + 4 * q);
                    #pragma unroll
                    for (int i = 0; i < 4; ++i) {
                        uint32_t zi = (&zz.x)[i];
                        a0 = dot2f(w4[4 * q + i],      zi, a0);
                        a1 = dot2f(w4[16 + 4 * q + i], zi, a1);
                        a2 = dot2f(w4[32 + 4 * q + i], zi, a2);
                    }
                }
                a0 = qsum4(a0);
                a1 = qsum4(a1);
                a2 = qsum4(a2);
                if (kq == 0) {
                    pp[c]       = tanh_fast(bo0 + a0) * dxs[m0];
                    pp[c + 128] = tanh_fast(bo1 + a1) * dxs[m1];
                    pp[c + 256] = tanh_fast(bo2 + a2) * dxs[m2];
                }
            }
            __syncthreads();

            // ---- k = A @ dX; RK4 bookkeeping; next vf input (wave 0) ----
            if (t < H_) {
                const float* pr = &pp[t * 6];
                float kv = pr[0] + pr[1] + pr[2] + pr[3] + pr[4] + pr[5];
                hacc += ((s4 == 1 || s4 == 2) ? 2.0f : 1.0f) * kv;
                float hs;
                if (s4 < 3) {
                    hs = h_reg + ((s4 == 2) ? 1.0f : 0.5f) * kv;
                } else {
                    h_reg += hacc * (1.0f / 6.0f);
                    hacc = 0.f;
                    hbuf[t] = h_reg;
                    hs = h_reg;
                }
                ((_Float16*)hinu)[t] = (_Float16)hs;
            }
            __syncthreads();
        }

        // ---- out for tt = step+1 (wave 0) ----
        if (t < 64) {
            int o = t & 7, part = t >> 3;
            float s = 0.f;
            #pragma unroll
            for (int j = 0; j < 8; ++j) s += hbuf[part * 8 + j] * wfr[j];
            s += __shfl_xor(s, 8);
            s += __shfl_xor(s, 16);
            s += __shfl_xor(s, 32);
            if (part == 0) out[obase + (size_t)(step + 1) * OUT_ + o] = s + bfin_r;
        }
    }
}

} // namespace

extern "C" void kernel_launch(void* const* d_in, const int* in_sizes, int n_in,
                              void* d_out, int out_size, void* d_ws, size_t ws_size,
                              hipStream_t stream) {
    const float* x      = (const float*)d_in[0];
    const float* W_init = (const float*)d_in[1];
    const float* b_init = (const float*)d_in[2];
    const float* W_in   = (const float*)d_in[3];
    const float* b_in   = (const float*)d_in[4];
    const float* W_h1   = (const float*)d_in[5];
    const float* b_h1   = (const float*)d_in[6];
    const float* W_h2   = (const float*)d_in[7];
    const float* b_h2   = (const float*)d_in[8];
    const float* W_out  = (const float*)d_in[9];
    const float* b_out  = (const float*)d_in[10];
    const float* W_fin  = (const float*)d_in[11];
    const float* b_fin  = (const float*)d_in[12];
    float* out = (float*)d_out;

    cde_kernel<<<dim3(B_), dim3(512), 0, stream>>>(
        x, W_init, b_init, W_in, b_in, W_h1, b_h1, W_h2, b_h2,
        W_out, b_out, W_fin, b_fin, out);
}

// Round 7
// 4508.078 us; speedup vs baseline: 1.1917x; 1.1917x over previous
//
#include <hip/hip_runtime.h>
#include <stdint.h>

namespace {

constexpr int B_   = 512;
constexpr int T_   = 512;
constexpr int IN_  = 6;
constexpr int H_   = 64;
constexpr int HH_  = 128;
constexpr int OUT_ = 8;

typedef _Float16 f16x2 __attribute__((ext_vector_type(2)));

__device__ __forceinline__ float dot2f(uint32_t w, uint32_t z, float acc) {
    return __builtin_amdgcn_fdot2(__builtin_bit_cast(f16x2, w),
                                  __builtin_bit_cast(f16x2, z), acc, false);
}

__device__ __forceinline__ uint32_t pack2f(float a, float b) {
    f16x2 p;
    p[0] = (_Float16)a;
    p[1] = (_Float16)b;
    return __builtin_bit_cast(uint32_t, p);
}

// sum across a 4-lane quad (kq = lane&3) via DPP quad_perm — pure VALU.
__device__ __forceinline__ float qsum4(float v) {
    int y = __builtin_amdgcn_mov_dpp(__builtin_bit_cast(int, v), 0xB1, 0xF, 0xF, true); // xor1
    v += __builtin_bit_cast(float, y);
    y = __builtin_amdgcn_mov_dpp(__builtin_bit_cast(int, v), 0x4E, 0xF, 0xF, true);     // xor2
    return v + __builtin_bit_cast(float, y);
}

__device__ __forceinline__ float tanh_fast(float v) {
    float ax = fabsf(v);
    float e  = __expf(2.0f * ax);
    float r  = 1.0f - 2.0f / (e + 1.0f);
    return copysignf(r, v);
}

// One workgroup (256 threads) per TWO batch elements (grid 256 = 1 block/CU).
//   thread t: col-slot cs = t>>2 (owns z-cols {cs, cs+64} and A-row cs),
//   k-quarter kq = t&3. Weights (176 u32, f16 pairs) shared by both elements.
//   Quad reduction via DPP; einsum + RK4 fully in-register (kq==0 lanes).
//   4 barriers per vf eval (16/step).
__global__ __launch_bounds__(256, 1) void cde_kernel(
    const float* __restrict__ x,
    const float* __restrict__ W_init, const float* __restrict__ b_init,
    const float* __restrict__ W_in,   const float* __restrict__ b_in,
    const float* __restrict__ W_h1,   const float* __restrict__ b_h1,
    const float* __restrict__ W_h2,   const float* __restrict__ b_h2,
    const float* __restrict__ W_out,  const float* __restrict__ b_out,
    const float* __restrict__ W_fin,  const float* __restrict__ b_fin,
    float* __restrict__ out)
{
    const int t  = threadIdx.x;
    const int cs = t >> 2;      // 0..63
    const int kq = t & 3;       // k-quarter
    const int b0 = blockIdx.x * 2;

    __shared__ alignas(16) uint32_t hinu[2][H_ / 2];   // h as f16 (per elem)
    __shared__ alignas(16) uint32_t zAu[2][HH_ / 2];   // activation ping
    __shared__ alignas(16) uint32_t zBu[2][HH_ / 2];   // activation pong
    __shared__ float dxs[2][IN_];
    __shared__ float hbuf[2][H_];

    // ---- register-resident f16 weights (k-quarter slice, 2 cols / 6 A-cols) ----
    uint32_t w1[16], w2[32], w3[32], w4[96];
    #pragma unroll
    for (int i = 0; i < 8; ++i) {
        int k = kq * 16 + 2 * i;
        w1[i]     = pack2f(W_in[k * HH_ + cs],      W_in[(k + 1) * HH_ + cs]);
        w1[8 + i] = pack2f(W_in[k * HH_ + cs + 64], W_in[(k + 1) * HH_ + cs + 64]);
    }
    #pragma unroll
    for (int i = 0; i < 16; ++i) {
        int k = kq * 32 + 2 * i;
        w2[i]      = pack2f(W_h1[k * HH_ + cs],      W_h1[(k + 1) * HH_ + cs]);
        w2[16 + i] = pack2f(W_h1[k * HH_ + cs + 64], W_h1[(k + 1) * HH_ + cs + 64]);
        w3[i]      = pack2f(W_h2[k * HH_ + cs],      W_h2[(k + 1) * HH_ + cs]);
        w3[16 + i] = pack2f(W_h2[k * HH_ + cs + 64], W_h2[(k + 1) * HH_ + cs + 64]);
    }
    #pragma unroll
    for (int i = 0; i < 6; ++i) {
        int col = cs * 6 + i;
        #pragma unroll
        for (int m = 0; m < 16; ++m) {
            int k = kq * 32 + 2 * m;
            w4[i * 16 + m] = pack2f(W_out[k * 384 + col], W_out[(k + 1) * 384 + col]);
        }
    }
    const float bin0 = b_in[cs],  bin1 = b_in[cs + 64];
    const float bh10 = b_h1[cs],  bh11 = b_h1[cs + 64];
    const float bh20 = b_h2[cs],  bh21 = b_h2[cs + 64];
    float bo[6];
    #pragma unroll
    for (int i = 0; i < 6; ++i) bo[i] = b_out[cs * 6 + i];
    const float bfin_r = (t < 128) ? b_fin[t & 7] : 0.0f;

    float wfr[8];
    #pragma unroll
    for (int j = 0; j < 8; ++j)
        wfr[j] = (t < 128) ? W_fin[((((t & 63) >> 3)) * 8 + j) * OUT_ + (t & 7)] : 0.0f;

    const size_t xb0 = (size_t)b0 * T_ * IN_;
    const size_t xb1 = (size_t)(b0 + 1) * T_ * IN_;

    // dX producers: t<6 -> elem0 dim t; 6<=t<12 -> elem1 dim t-6.
    const int    dde = (t < 6) ? 0 : 1;
    const int    ddi = (t < 6) ? t : t - 6;
    const size_t xbase_d = (dde == 0) ? xb0 : xb1;
    float xa = 0.f, xb = 0.f;
    if (t < 12) {
        xa = x[xbase_d + ddi];
        xb = x[xbase_d + IN_ + ddi];
        dxs[dde][ddi] = xb - xa;                 // dX for step 0
        xa = xb;
        xb = x[xbase_d + 2 * IN_ + ddi];
    }

    // ---- h0 (threads t<128: e = t>>6, row r = t&63) ----
    if (t < 128) {
        int e = t >> 6, r = t & 63;
        size_t xbe = e ? xb1 : xb0;
        float s = b_init[r];
        #pragma unroll
        for (int i = 0; i < IN_; ++i) s += x[xbe + i] * W_init[i * H_ + r];
        hbuf[e][r] = s;
        ((_Float16*)hinu[e])[r] = (_Float16)s;
    }
    __syncthreads();

    // RK4 state lives in kq==0 lanes (thread 4*cs), both elements.
    float h_reg[2], hacc[2] = {0.f, 0.f};
    h_reg[0] = hbuf[0][cs];
    h_reg[1] = hbuf[1][cs];

#define OUT_STAGE(TT)                                                          \
    if (t < 128) {                                                             \
        int e_ = t >> 6, o_ = t & 7, part_ = (t & 63) >> 3;                    \
        float s_ = 0.f;                                                        \
        _Pragma("unroll")                                                      \
        for (int j = 0; j < 8; ++j) s_ += hbuf[e_][part_ * 8 + j] * wfr[j];    \
        s_ += __shfl_xor(s_, 8);                                               \
        s_ += __shfl_xor(s_, 16);                                              \
        s_ += __shfl_xor(s_, 32);                                              \
        if (part_ == 0)                                                        \
            out[(size_t)(b0 + e_) * T_ * OUT_ + (size_t)(TT) * OUT_ + o_] = s_ + bfin_r; \
    }

    OUT_STAGE(0)

    float dxr[2][6];

    for (int step = 0; step < T_ - 1; ++step) {
        #pragma unroll
        for (int s4 = 0; s4 < 4; ++s4) {
            // ---- phase 1: (dx reload + out-stage on s4==0) + G1: h -> z1 ----
            if (s4 == 0) {
                #pragma unroll
                for (int e = 0; e < 2; ++e)
                    #pragma unroll
                    for (int i = 0; i < 6; ++i) dxr[e][i] = dxs[e][i];
                if (step > 0) { OUT_STAGE(step) }
            }
            #pragma unroll
            for (int e = 0; e < 2; ++e) {
                const uint32_t* hp = hinu[e] + kq * 8;
                uint4 q0 = *reinterpret_cast<const uint4*>(hp);
                uint4 q1 = *reinterpret_cast<const uint4*>(hp + 4);
                float a = 0.f, d = 0.f;
                #pragma unroll
                for (int m = 0; m < 4; ++m) {
                    a = dot2f(w1[m],      (&q0.x)[m], a);
                    d = dot2f(w1[8 + m],  (&q0.x)[m], d);
                    a = dot2f(w1[4 + m],  (&q1.x)[m], a);
                    d = dot2f(w1[12 + m], (&q1.x)[m], d);
                }
                a = qsum4(a); d = qsum4(d);
                if (kq == 0)      ((_Float16*)zAu[e])[cs]      = (_Float16)fmaxf(bin0 + a, 0.f);
                else if (kq == 1) ((_Float16*)zAu[e])[cs + 64] = (_Float16)fmaxf(bin1 + d, 0.f);
            }
            __syncthreads();

            // ---- phase 2: G2 zA -> zB ----
            #pragma unroll
            for (int e = 0; e < 2; ++e) {
                const uint32_t* zp = zAu[e] + kq * 16;
                uint4 q0 = *reinterpret_cast<const uint4*>(zp);
                uint4 q1 = *reinterpret_cast<const uint4*>(zp + 4);
                uint4 q2 = *reinterpret_cast<const uint4*>(zp + 8);
                uint4 q3 = *reinterpret_cast<const uint4*>(zp + 12);
                float a = 0.f, d = 0.f;
                #pragma unroll
                for (int m = 0; m < 4; ++m) {
                    a = dot2f(w2[m],      (&q0.x)[m], a);  d = dot2f(w2[16 + m], (&q0.x)[m], d);
                    a = dot2f(w2[4 + m],  (&q1.x)[m], a);  d = dot2f(w2[20 + m], (&q1.x)[m], d);
                    a = dot2f(w2[8 + m],  (&q2.x)[m], a);  d = dot2f(w2[24 + m], (&q2.x)[m], d);
                    a = dot2f(w2[12 + m], (&q3.x)[m], a);  d = dot2f(w2[28 + m], (&q3.x)[m], d);
                }
                a = qsum4(a); d = qsum4(d);
                if (kq == 0)      ((_Float16*)zBu[e])[cs]      = (_Float16)fmaxf(bh10 + a, 0.f);
                else if (kq == 1) ((_Float16*)zBu[e])[cs + 64] = (_Float16)fmaxf(bh11 + d, 0.f);
            }
            __syncthreads();

            // ---- phase 3: G3 zB -> zA ----
            #pragma unroll
            for (int e = 0; e < 2; ++e) {
                const uint32_t* zp = zBu[e] + kq * 16;
                uint4 q0 = *reinterpret_cast<const uint4*>(zp);
                uint4 q1 = *reinterpret_cast<const uint4*>(zp + 4);
                uint4 q2 = *reinterpret_cast<const uint4*>(zp + 8);
                uint4 q3 = *reinterpret_cast<const uint4*>(zp + 12);
                float a = 0.f, d = 0.f;
                #pragma unroll
                for (int m = 0; m < 4; ++m) {
                    a = dot2f(w3[m],      (&q0.x)[m], a);  d = dot2f(w3[16 + m], (&q0.x)[m], d);
                    a = dot2f(w3[4 + m],  (&q1.x)[m], a);  d = dot2f(w3[20 + m], (&q1.x)[m], d);
                    a = dot2f(w3[8 + m],  (&q2.x)[m], a);  d = dot2f(w3[24 + m], (&q2.x)[m], d);
                    a = dot2f(w3[12 + m], (&q3.x)[m], a);  d = dot2f(w3[28 + m], (&q3.x)[m], d);
                }
                a = qsum4(a); d = qsum4(d);
                if (kq == 0)      ((_Float16*)zAu[e])[cs]      = (_Float16)fmaxf(bh20 + a, 0.f);
                else if (kq == 1) ((_Float16*)zAu[e])[cs + 64] = (_Float16)fmaxf(bh21 + d, 0.f);
            }
            __syncthreads();

            // ---- phase 4: G4 (z3 -> A-row cs) + in-register einsum + RK4 ----
            #pragma unroll
            for (int e = 0; e < 2; ++e) {
                const uint32_t* zp = zAu[e] + kq * 16;
                uint4 q0 = *reinterpret_cast<const uint4*>(zp);
                uint4 q1 = *reinterpret_cast<const uint4*>(zp + 4);
                uint4 q2 = *reinterpret_cast<const uint4*>(zp + 8);
                uint4 q3 = *reinterpret_cast<const uint4*>(zp + 12);
                float av0 = 0.f, av1 = 0.f, av2 = 0.f, av3 = 0.f, av4 = 0.f, av5 = 0.f;
                #pragma unroll
                for (int m = 0; m < 4; ++m) {
                    uint32_t z0 = (&q0.x)[m], z1 = (&q1.x)[m], z2 = (&q2.x)[m], z3 = (&q3.x)[m];
                    av0 = dot2f(w4[m],      z0, av0); av0 = dot2f(w4[4 + m],   z1, av0);
                    av0 = dot2f(w4[8 + m],  z2, av0); av0 = dot2f(w4[12 + m],  z3, av0);
                    av1 = dot2f(w4[16 + m], z0, av1); av1 = dot2f(w4[20 + m],  z1, av1);
                    av1 = dot2f(w4[24 + m], z2, av1); av1 = dot2f(w4[28 + m],  z3, av1);
                    av2 = dot2f(w4[32 + m], z0, av2); av2 = dot2f(w4[36 + m],  z1, av2);
                    av2 = dot2f(w4[40 + m], z2, av2); av2 = dot2f(w4[44 + m],  z3, av2);
                    av3 = dot2f(w4[48 + m], z0, av3); av3 = dot2f(w4[52 + m],  z1, av3);
                    av3 = dot2f(w4[56 + m], z2, av3); av3 = dot2f(w4[60 + m],  z3, av3);
                    av4 = dot2f(w4[64 + m], z0, av4); av4 = dot2f(w4[68 + m],  z1, av4);
                    av4 = dot2f(w4[72 + m], z2, av4); av4 = dot2f(w4[76 + m],  z3, av4);
                    av5 = dot2f(w4[80 + m], z0, av5); av5 = dot2f(w4[84 + m],  z1, av5);
                    av5 = dot2f(w4[88 + m], z2, av5); av5 = dot2f(w4[92 + m],  z3, av5);
                }
                av0 = qsum4(av0); av1 = qsum4(av1); av2 = qsum4(av2);
                av3 = qsum4(av3); av4 = qsum4(av4); av5 = qsum4(av5);
                if (kq == 0) {
                    float kv = tanh_fast(bo[0] + av0) * dxr[e][0]
                             + tanh_fast(bo[1] + av1) * dxr[e][1]
                             + tanh_fast(bo[2] + av2) * dxr[e][2]
                             + tanh_fast(bo[3] + av3) * dxr[e][3]
                             + tanh_fast(bo[4] + av4) * dxr[e][4]
                             + tanh_fast(bo[5] + av5) * dxr[e][5];
                    hacc[e] += ((s4 == 1 || s4 == 2) ? 2.0f : 1.0f) * kv;
                    float hs;
                    if (s4 < 3) {
                        hs = h_reg[e] + ((s4 == 2) ? 1.0f : 0.5f) * kv;
                    } else {
                        h_reg[e] += hacc[e] * (1.0f / 6.0f);
                        hacc[e] = 0.f;
                        hbuf[e][cs] = h_reg[e];
                        hs = h_reg[e];
                    }
                    ((_Float16*)hinu[e])[cs] = (_Float16)hs;
                }
            }
            // dX for step+1 (read at next step's s4==0, after the barrier below)
            if (s4 == 3 && step + 2 < T_ && t < 12) {
                dxs[dde][ddi] = xb - xa;
                xa = xb;
                if (step + 3 < T_) xb = x[xbase_d + (size_t)(step + 3) * IN_ + ddi];
            }
            __syncthreads();
        }
    }

    OUT_STAGE(T_ - 1)
#undef OUT_STAGE
}

} // namespace

extern "C" void kernel_launch(void* const* d_in, const int* in_sizes, int n_in,
                              void* d_out, int out_size, void* d_ws, size_t ws_size,
                              hipStream_t stream) {
    const float* x      = (const float*)d_in[0];
    const float* W_init = (const float*)d_in[1];
    const float* b_init = (const float*)d_in[2];
    const float* W_in   = (const float*)d_in[3];
    const float* b_in   = (const float*)d_in[4];
    const float* W_h1   = (const float*)d_in[5];
    const float* b_h1   = (const float*)d_in[6];
    const float* W_h2   = (const float*)d_in[7];
    const float* b_h2   = (const float*)d_in[8];
    const float* W_out  = (const float*)d_in[9];
    const float* b_out  = (const float*)d_in[10];
    const float* W_fin  = (const float*)d_in[11];
    const float* b_fin  = (const float*)d_in[12];
    float* out = (float*)d_out;

    cde_kernel<<<dim3(B_ / 2), dim3(256), 0, stream>>>(
        x, W_init, b_init, W_in, b_in, W_h1, b_h1, W_h2, b_h2,
        W_out, b_out, W_fin, b_fin, out);
}

// Round 8
// 3929.538 us; speedup vs baseline: 1.3671x; 1.1472x over previous
//
#include <hip/hip_runtime.h>
#include <stdint.h>

namespace {

constexpr int B_   = 512;
constexpr int T_   = 512;
constexpr int IN_  = 6;
constexpr int H_   = 64;
constexpr int HH_  = 128;
constexpr int OUT_ = 8;

typedef _Float16 f16x2 __attribute__((ext_vector_type(2)));

__device__ __forceinline__ float dot2f(uint32_t w, uint32_t z, float acc) {
    return __builtin_amdgcn_fdot2(__builtin_bit_cast(f16x2, w),
                                  __builtin_bit_cast(f16x2, z), acc, false);
}

__device__ __forceinline__ uint32_t pack2f(float a, float b) {
    f16x2 p;
    p[0] = (_Float16)a;
    p[1] = (_Float16)b;
    return __builtin_bit_cast(uint32_t, p);
}

// sum across a 4-lane quad (kq = lane&3) via DPP quad_perm — pure VALU.
__device__ __forceinline__ float qsum4(float v) {
    int y = __builtin_amdgcn_mov_dpp(__builtin_bit_cast(int, v), 0xB1, 0xF, 0xF, true); // xor1
    v += __builtin_bit_cast(float, y);
    y = __builtin_amdgcn_mov_dpp(__builtin_bit_cast(int, v), 0x4E, 0xF, 0xF, true);     // xor2
    return v + __builtin_bit_cast(float, y);
}

__device__ __forceinline__ float tanh_fast(float v) {
    float ax = fabsf(v);
    float e  = __expf(2.0f * ax);
    float r  = 1.0f - 2.0f / (e + 1.0f);
    return copysignf(r, v);
}

// One workgroup (512 threads) per TWO batch elements. Grid 256 = 1 block/CU,
// 8 waves = 2/SIMD. Thread t: col c = t>>2 (one z-column), k-quarter kq = t&3,
// processes BOTH elements -> weights 88 u32/thread, zero duplication.
// W_out cols {3c,3c+1,3c+2} -> A-row c>>1, dims (c&1)*3+{0,1,2}; row summed
// via __shfl_xor(4). RK4 state in kq==0 lanes (128 = 2 elems x 64 rows).
__global__ __launch_bounds__(512, 2) void cde_kernel(
    const float* __restrict__ x,
    const float* __restrict__ W_init, const float* __restrict__ b_init,
    const float* __restrict__ W_in,   const float* __restrict__ b_in,
    const float* __restrict__ W_h1,   const float* __restrict__ b_h1,
    const float* __restrict__ W_h2,   const float* __restrict__ b_h2,
    const float* __restrict__ W_out,  const float* __restrict__ b_out,
    const float* __restrict__ W_fin,  const float* __restrict__ b_fin,
    float* __restrict__ out)
{
    const int t  = threadIdx.x;
    const int c  = t >> 2;      // 0..127 (z-column)
    const int kq = t & 3;       // k-quarter
    const int b0 = blockIdx.x * 2;

    __shared__ alignas(16) uint32_t hinu[2][H_ / 2];   // h as f16 per elem
    __shared__ alignas(16) uint32_t zAu[2][HH_ / 2];   // activation ping
    __shared__ alignas(16) uint32_t zBu[2][HH_ / 2];   // activation pong
    __shared__ float dxs[2][IN_];
    __shared__ float hbuf[2][H_];

    // ---- register-resident f16 weights: 8+16+16+48 = 88 u32, no duplication ----
    uint32_t w1[8], w2[16], w3[16], w4[48];
    #pragma unroll
    for (int i = 0; i < 8; ++i) {
        int k = kq * 16 + 2 * i;
        w1[i] = pack2f(W_in[k * HH_ + c], W_in[(k + 1) * HH_ + c]);
    }
    #pragma unroll
    for (int i = 0; i < 16; ++i) {
        int k = kq * 32 + 2 * i;
        w2[i] = pack2f(W_h1[k * HH_ + c], W_h1[(k + 1) * HH_ + c]);
        w3[i] = pack2f(W_h2[k * HH_ + c], W_h2[(k + 1) * HH_ + c]);
    }
    #pragma unroll
    for (int j = 0; j < 3; ++j) {
        const int col = 3 * c + j;
        #pragma unroll
        for (int i = 0; i < 16; ++i) {
            int k = kq * 32 + 2 * i;
            w4[j * 16 + i] = pack2f(W_out[k * 384 + col], W_out[(k + 1) * 384 + col]);
        }
    }
    const float bin_r = b_in[c];
    const float bh1_r = b_h1[c];
    const float bh2_r = b_h2[c];
    float bo[3];
    #pragma unroll
    for (int j = 0; j < 3; ++j) bo[j] = b_out[3 * c + j];
    const int   dbase = (c & 1) * 3;     // dim offset of this thread's 3 A-cols
    const int   e_own = c & 1;           // state lane's element (kq==0)
    const int   r_own = c >> 1;          // state lane's h-row
    const float bfin_r = (t < 128) ? b_fin[t & 7] : 0.0f;

    float wfr[8];
    #pragma unroll
    for (int j = 0; j < 8; ++j)
        wfr[j] = (t < 128) ? W_fin[((((t & 63) >> 3)) * 8 + j) * OUT_ + (t & 7)] : 0.0f;

    const size_t xb0 = (size_t)b0 * T_ * IN_;
    const size_t xb1 = (size_t)(b0 + 1) * T_ * IN_;

    // dX producers: t<6 -> elem0 dim t; 6<=t<12 -> elem1 dim t-6.
    const int    dde = (t < 6) ? 0 : 1;
    const int    ddi = (t < 6) ? t : t - 6;
    const size_t xbase_d = (dde == 0) ? xb0 : xb1;
    float xa = 0.f, xb = 0.f;
    if (t < 12) {
        xa = x[xbase_d + ddi];
        xb = x[xbase_d + IN_ + ddi];
        dxs[dde][ddi] = xb - xa;                 // dX for step 0
        xa = xb;
        xb = x[xbase_d + 2 * IN_ + ddi];
    }

    // ---- h0 (threads t<128: e = t>>6, row r = t&63) ----
    if (t < 128) {
        int e = t >> 6, r = t & 63;
        size_t xbe = e ? xb1 : xb0;
        float s = b_init[r];
        #pragma unroll
        for (int i = 0; i < IN_; ++i) s += x[xbe + i] * W_init[i * H_ + r];
        hbuf[e][r] = s;
        ((_Float16*)hinu[e])[r] = (_Float16)s;
    }
    __syncthreads();

    // RK4 state (meaningful in kq==0 lanes only)
    float h_reg = hbuf[e_own][r_own];
    float hacc  = 0.f;

#define OUT_STAGE(TT)                                                          \
    if (t < 128) {                                                             \
        int e_ = t >> 6, o_ = t & 7, part_ = (t & 63) >> 3;                    \
        float s_ = 0.f;                                                        \
        _Pragma("unroll")                                                      \
        for (int j = 0; j < 8; ++j) s_ += hbuf[e_][part_ * 8 + j] * wfr[j];    \
        s_ += __shfl_xor(s_, 8);                                               \
        s_ += __shfl_xor(s_, 16);                                              \
        s_ += __shfl_xor(s_, 32);                                              \
        if (part_ == 0)                                                        \
            out[(size_t)(b0 + e_) * T_ * OUT_ + (size_t)(TT) * OUT_ + o_] = s_ + bfin_r; \
    }

    OUT_STAGE(0)

    float dxr[2][3];

    for (int step = 0; step < T_ - 1; ++step) {
        #pragma unroll
        for (int s4 = 0; s4 < 4; ++s4) {
            // ---- phase 1: (dx reload + out-stage on s4==0) + G1: h -> z1 ----
            if (s4 == 0) {
                #pragma unroll
                for (int e = 0; e < 2; ++e)
                    #pragma unroll
                    for (int j = 0; j < 3; ++j) dxr[e][j] = dxs[e][dbase + j];
                if (step > 0) { OUT_STAGE(step) }
            }
            #pragma unroll
            for (int e = 0; e < 2; ++e) {
                const uint32_t* hp = hinu[e] + kq * 8;
                uint4 q0 = *reinterpret_cast<const uint4*>(hp);
                uint4 q1 = *reinterpret_cast<const uint4*>(hp + 4);
                float a = 0.f, d = 0.f;
                a = dot2f(w1[0], q0.x, a); d = dot2f(w1[1], q0.y, d);
                a = dot2f(w1[2], q0.z, a); d = dot2f(w1[3], q0.w, d);
                a = dot2f(w1[4], q1.x, a); d = dot2f(w1[5], q1.y, d);
                a = dot2f(w1[6], q1.z, a); d = dot2f(w1[7], q1.w, d);
                float z = fmaxf(bin_r + qsum4(a + d), 0.f);
                if (kq == e) ((_Float16*)zAu[e])[c] = (_Float16)z;
            }
            __syncthreads();

            // ---- phase 2: G2 zA -> zB ----
            #pragma unroll
            for (int e = 0; e < 2; ++e) {
                const uint32_t* zp = zAu[e] + kq * 16;
                uint4 q0 = *reinterpret_cast<const uint4*>(zp);
                uint4 q1 = *reinterpret_cast<const uint4*>(zp + 4);
                uint4 q2 = *reinterpret_cast<const uint4*>(zp + 8);
                uint4 q3 = *reinterpret_cast<const uint4*>(zp + 12);
                float a = 0.f, d = 0.f;
                #pragma unroll
                for (int m = 0; m < 4; ++m) {
                    a = dot2f(w2[m],      (&q0.x)[m], a);
                    d = dot2f(w2[4 + m],  (&q1.x)[m], d);
                    a = dot2f(w2[8 + m],  (&q2.x)[m], a);
                    d = dot2f(w2[12 + m], (&q3.x)[m], d);
                }
                float z = fmaxf(bh1_r + qsum4(a + d), 0.f);
                if (kq == e) ((_Float16*)zBu[e])[c] = (_Float16)z;
            }
            __syncthreads();

            // ---- phase 3: G3 zB -> zA ----
            #pragma unroll
            for (int e = 0; e < 2; ++e) {
                const uint32_t* zp = zBu[e] + kq * 16;
                uint4 q0 = *reinterpret_cast<const uint4*>(zp);
                uint4 q1 = *reinterpret_cast<const uint4*>(zp + 4);
                uint4 q2 = *reinterpret_cast<const uint4*>(zp + 8);
                uint4 q3 = *reinterpret_cast<const uint4*>(zp + 12);
                float a = 0.f, d = 0.f;
                #pragma unroll
                for (int m = 0; m < 4; ++m) {
                    a = dot2f(w3[m],      (&q0.x)[m], a);
                    d = dot2f(w3[4 + m],  (&q1.x)[m], d);
                    a = dot2f(w3[8 + m],  (&q2.x)[m], a);
                    d = dot2f(w3[12 + m], (&q3.x)[m], d);
                }
                float z = fmaxf(bh2_r + qsum4(a + d), 0.f);
                if (kq == e) ((_Float16*)zAu[e])[c] = (_Float16)z;
            }
            __syncthreads();

            // ---- phase 4: G4 (3 A-cols) + pair-sum einsum + RK4 ----
            float kvf[2];
            #pragma unroll
            for (int e = 0; e < 2; ++e) {
                const uint32_t* zp = zAu[e] + kq * 16;
                uint4 q0 = *reinterpret_cast<const uint4*>(zp);
                uint4 q1 = *reinterpret_cast<const uint4*>(zp + 4);
                uint4 q2 = *reinterpret_cast<const uint4*>(zp + 8);
                uint4 q3 = *reinterpret_cast<const uint4*>(zp + 12);
                float av0 = 0.f, av1 = 0.f, av2 = 0.f;
                #pragma unroll
                for (int m = 0; m < 4; ++m) {
                    uint32_t z0 = (&q0.x)[m], z1 = (&q1.x)[m], z2 = (&q2.x)[m], z3 = (&q3.x)[m];
                    av0 = dot2f(w4[m],      z0, av0); av0 = dot2f(w4[4 + m],  z1, av0);
                    av0 = dot2f(w4[8 + m],  z2, av0); av0 = dot2f(w4[12 + m], z3, av0);
                    av1 = dot2f(w4[16 + m], z0, av1); av1 = dot2f(w4[20 + m], z1, av1);
                    av1 = dot2f(w4[24 + m], z2, av1); av1 = dot2f(w4[28 + m], z3, av1);
                    av2 = dot2f(w4[32 + m], z0, av2); av2 = dot2f(w4[36 + m], z1, av2);
                    av2 = dot2f(w4[40 + m], z2, av2); av2 = dot2f(w4[44 + m], z3, av2);
                }
                av0 = qsum4(av0); av1 = qsum4(av1); av2 = qsum4(av2);
                float kvp = tanh_fast(bo[0] + av0) * dxr[e][0]
                          + tanh_fast(bo[1] + av1) * dxr[e][1]
                          + tanh_fast(bo[2] + av2) * dxr[e][2];
                kvf[e] = kvp + __shfl_xor(kvp, 4);   // pair (2r,2r+1) -> full row sum
            }
            {
                float kv = kvf[e_own];
                hacc += ((s4 == 1 || s4 == 2) ? 2.0f : 1.0f) * kv;
                float hs;
                if (s4 < 3) {
                    hs = h_reg + ((s4 == 2) ? 1.0f : 0.5f) * kv;
                } else {
                    h_reg += hacc * (1.0f / 6.0f);
                    hacc = 0.f;
                    hs = h_reg;
                }
                if (kq == 0) {
                    ((_Float16*)hinu[e_own])[r_own] = (_Float16)hs;
                    if (s4 == 3) hbuf[e_own][r_own] = h_reg;
                }
            }
            // dX for step+1 (read at next step's s4==0, after the barrier below)
            if (s4 == 3 && step + 2 < T_ && t < 12) {
                dxs[dde][ddi] = xb - xa;
                xa = xb;
                if (step + 3 < T_) xb = x[xbase_d + (size_t)(step + 3) * IN_ + ddi];
            }
            __syncthreads();
        }
    }

    OUT_STAGE(T_ - 1)
#undef OUT_STAGE
}

} // namespace

extern "C" void kernel_launch(void* const* d_in, const int* in_sizes, int n_in,
                              void* d_out, int out_size, void* d_ws, size_t ws_size,
                              hipStream_t stream) {
    const float* x      = (const float*)d_in[0];
    const float* W_init = (const float*)d_in[1];
    const float* b_init = (const float*)d_in[2];
    const float* W_in   = (const float*)d_in[3];
    const float* b_in   = (const float*)d_in[4];
    const float* W_h1   = (const float*)d_in[5];
    const float* b_h1   = (const float*)d_in[6];
    const float* W_h2   = (const float*)d_in[7];
    const float* b_h2   = (const float*)d_in[8];
    const float* W_out  = (const float*)d_in[9];
    const float* b_out  = (const float*)d_in[10];
    const float* W_fin  = (const float*)d_in[11];
    const float* b_fin  = (const float*)d_in[12];
    float* out = (float*)d_out;

    cde_kernel<<<dim3(B_ / 2), dim3(512), 0, stream>>>(
        x, W_init, b_init, W_in, b_in, W_h1, b_h1, W_h2, b_h2,
        W_out, b_out, W_fin, b_fin, out);
}